// Round 3
// baseline (22884.515 us; speedup 1.0000x reference)
//
#include <hip/hip_runtime.h>
#include <math.h>

// ---------------------------------------------------------------------------
// LSTM-CRF (B=64,T=512,E=256,H=256,K=32,V=50000), all f32.
// Chunked xg (CS=64 steps) to keep workspace ~173 MB.
// Layouts (lane = batch everywhere in the sequential phases):
//   xg  [dir][ls(64)][gate(1024)][b]   (per-chunk, reused)
//   out [t][unit(512)][b]              (unit = dir*256+u)
//   em  [t][b][tag(32)]
// ---------------------------------------------------------------------------

constexpr int TLEN = 512, CS = 64, NCH = 8;

constexpr size_t O_OUT0 = 0;
constexpr size_t N_OUT  = (size_t)TLEN * 512 * 64;          // 16,777,216
constexpr size_t O_OUT1 = O_OUT0 + N_OUT;
constexpr size_t O_XG   = O_OUT1 + N_OUT;
constexpr size_t N_XG   = (size_t)2 * CS * 1024 * 64;       // 8,388,608
constexpr size_t O_EM   = O_XG + N_XG;
constexpr size_t N_EM   = (size_t)TLEN * 64 * 32;           // 1,048,576
constexpr size_t O_HBUF = O_EM + N_EM;                      // [2L][2d][2p][256][64]
constexpr size_t N_HBUF = (size_t)2 * 2 * 2 * 256 * 64;     // 131,072
constexpr size_t O_CST  = O_HBUF + N_HBUF;                  // [2L][2d][256][64]
constexpr size_t N_CST  = (size_t)2 * 2 * 256 * 64;         // 65,536
constexpr size_t O_FLG  = O_CST + N_CST;                    // [2L][2d][512][64] ints
constexpr size_t N_FLG  = (size_t)2 * 2 * 512 * 64;         // 131,072
constexpr size_t WS_FLOATS = O_FLG + N_FLG;                 // 43,319,296 (~173 MB)

// ---------------------------------------------------------------------- init
__global__ __launch_bounds__(256) void initz(float* hbuf, float* cst, int* flg,
                                             float* dout) {
  int i = blockIdx.x * 256 + threadIdx.x;  // grid 512 -> 131072 threads
  if (i < (int)N_HBUF) hbuf[i] = 0.f;
  if (i < (int)N_CST) cst[i] = 0.f;
  if (i < (int)N_FLG) flg[i] = 0;
  if (i == 0) dout[0] = 0.f;
}

__global__ void ws_too_small_k(float* dout, int n) {
  int i = blockIdx.x * 256 + threadIdx.x;
  if (i < n) dout[i] = 1e30f;  // clean diagnostic failure, no fault
}

// ------------------------------------------------------------------- GEMM
// xg[d][ls][n][b] = A_row(t(b,ls)) . W[n] + bias[n]  for steps s in [s0,s0+CS)
// AMODE 0: A = emb table, rows gathered via ids (layer 0, K=256).
// AMODE 1: A = out0 [t][512][b] (layer 1, K=512).
template <int KTOT, int AMODE>
__global__ __launch_bounds__(256)
void gemm_xg(const float* __restrict__ A, const int* __restrict__ ids,
             const float* __restrict__ Wf, const float* __restrict__ Wb,
             const float* __restrict__ bf, const float* __restrict__ bb,
             float* __restrict__ xg, int s0) {
  constexpr int BK = 16;
  __shared__ float As[BK][132];
  __shared__ float Bs[BK][132];
  const int tid = threadIdx.x;
  const int m0 = blockIdx.x * 128, n0 = blockIdx.y * 128, d = blockIdx.z;
  const float* W = d ? Wb : Wf;
  const float* bias = d ? bb : bf;
  const int mg = tid & 15, ng = tid >> 4;
  const int rb = tid >> 2;            // 0..63
  const int kq = (tid & 3) << 2;      // 0,4,8,12
  const int ls0 = m0 >> 6;            // first local step of this M-tile

  int arow[2];  // AMODE0: emb row ids ; AMODE1: time t
  #pragma unroll
  for (int p = 0; p < 2; ++p) {
    int s = s0 + ls0 + p;
    int t = d ? (TLEN - 1 - s) : s;
    arow[p] = (AMODE == 0) ? ids[rb * TLEN + t] : t;
  }

  float acc[8][8];
  #pragma unroll
  for (int i = 0; i < 8; ++i)
    #pragma unroll
    for (int j = 0; j < 8; ++j) acc[i][j] = 0.f;

  for (int kt = 0; kt < KTOT; kt += BK) {
    if (AMODE == 0) {
      #pragma unroll
      for (int p = 0; p < 2; ++p) {
        float4 v = *reinterpret_cast<const float4*>(A + (size_t)arow[p] * KTOT + kt + kq);
        int r = p * 64 + rb;
        As[kq + 0][r] = v.x; As[kq + 1][r] = v.y;
        As[kq + 2][r] = v.z; As[kq + 3][r] = v.w;
      }
    } else {
      const int b = tid & 63;
      #pragma unroll
      for (int p = 0; p < 8; ++p) {
        int flat = p * 4 + (tid >> 6);     // 0..31 = tl(2) x kk(16)
        int tl = flat >> 4, kk = flat & 15;
        As[kk][tl * 64 + b] = A[((size_t)arow[tl] * 512 + kt + kk) * 64 + b];
      }
    }
    #pragma unroll
    for (int p = 0; p < 2; ++p) {
      int r = p * 64 + rb;
      float4 v = *reinterpret_cast<const float4*>(W + (size_t)(n0 + r) * KTOT + kt + kq);
      Bs[kq + 0][r] = v.x; Bs[kq + 1][r] = v.y;
      Bs[kq + 2][r] = v.z; Bs[kq + 3][r] = v.w;
    }
    __syncthreads();
    #pragma unroll
    for (int k = 0; k < BK; ++k) {
      float a[8], w[8];
      #pragma unroll
      for (int i = 0; i < 8; ++i) a[i] = As[k][i * 16 + mg];
      float4 w0 = *reinterpret_cast<const float4*>(&Bs[k][ng * 8]);
      float4 w1 = *reinterpret_cast<const float4*>(&Bs[k][ng * 8 + 4]);
      w[0] = w0.x; w[1] = w0.y; w[2] = w0.z; w[3] = w0.w;
      w[4] = w1.x; w[5] = w1.y; w[6] = w1.z; w[7] = w1.w;
      #pragma unroll
      for (int i = 0; i < 8; ++i)
        #pragma unroll
        for (int j = 0; j < 8; ++j) acc[i][j] += a[i] * w[j];
    }
    __syncthreads();
  }
  #pragma unroll
  for (int j = 0; j < 8; ++j) {
    const int n = n0 + ng * 8 + j;
    const float bv = bias[n];
    #pragma unroll
    for (int i = 0; i < 8; ++i) {
      const int ml = i * 16 + mg;
      const int ls = ls0 + (ml >> 6);
      const int b = ml & 63;
      xg[(((size_t)d * CS + ls) * 1024 + n) * 64 + b] = acc[i][j] + bv;
    }
  }
}

// ------------------------------------------------------------- LSTM recurrence
// grid = 128: dir = bid>>6, hidden group g = bid&63 (4 units, one per wave).
// lane = batch. h broadcast via global hbuf (2-parity) + per-(step,g) flags.
static __device__ __forceinline__ float sigm(float x) { return 1.f / (1.f + expf(-x)); }

__global__ __launch_bounds__(256)
void lstm_rec(const float* __restrict__ xg, const float* __restrict__ whhf,
              const float* __restrict__ whhb, float* __restrict__ out,
              float* __restrict__ hbuf /*[2d][2p][256][64]*/,
              float* __restrict__ cst /*[2d][256][64]*/,
              int* __restrict__ flg /*[2d][512][64]*/, int s0) {
  const int d = blockIdx.x >> 6;
  const int g = blockIdx.x & 63;
  const int lane = threadIdx.x & 63;
  const int wv = threadIdx.x >> 6;
  const int u = g * 4 + wv;
  const float* whh = d ? whhb : whhf;
  const float* wi = whh + (size_t)u * 256;
  const float* wf_ = whh + (size_t)(256 + u) * 256;
  const float* wg_ = whh + (size_t)(512 + u) * 256;
  const float* wo_ = whh + (size_t)(768 + u) * 256;
  float* hb = hbuf + (size_t)d * 2 * 256 * 64;
  float* cs = cst + (size_t)d * 256 * 64;
  int* fl = flg + (size_t)d * TLEN * 64;
  __shared__ float hs[256][64];
  float c = cs[(size_t)u * 64 + lane];

  for (int ls = 0; ls < CS; ++ls) {
    const int s = s0 + ls;
    const int t = d ? (TLEN - 1 - s) : s;
    if (s > 0) {
      while (!__all(__hip_atomic_load(&fl[(size_t)(s - 1) * 64 + lane],
                                      __ATOMIC_ACQUIRE, __HIP_MEMORY_SCOPE_AGENT) != 0))
        __builtin_amdgcn_s_sleep(1);
    }
    {  // stage h_{s-1} (parity s&1) into LDS, 64 KB
      const float4* hp = reinterpret_cast<const float4*>(hb + (size_t)(s & 1) * 256 * 64);
      float4* hd = reinterpret_cast<float4*>(&hs[0][0]);
      #pragma unroll
      for (int q = 0; q < 16; ++q) hd[q * 256 + threadIdx.x] = hp[q * 256 + threadIdx.x];
    }
    __syncthreads();
    const size_t xb = ((size_t)d * CS + ls) * 1024;
    float xi = xg[(xb + u) * 64 + lane];
    float xf = xg[(xb + 256 + u) * 64 + lane];
    float xgv = xg[(xb + 512 + u) * 64 + lane];
    float xo = xg[(xb + 768 + u) * 64 + lane];
    float ai = 0.f, af = 0.f, ag = 0.f, ao = 0.f;
    #pragma unroll 4
    for (int k0 = 0; k0 < 256; k0 += 8) {
      float hk[8];
      #pragma unroll
      for (int q = 0; q < 8; ++q) hk[q] = hs[k0 + q][lane];
      #pragma unroll
      for (int q = 0; q < 8; ++q) {
        ai += hk[q] * wi[k0 + q];   // w*: wave-uniform -> scalar loads
        af += hk[q] * wf_[k0 + q];
        ag += hk[q] * wg_[k0 + q];
        ao += hk[q] * wo_[k0 + q];
      }
    }
    const float gi = sigm(xi + ai), gf = sigm(xf + af);
    const float gc = tanhf(xgv + ag), go = sigm(xo + ao);
    c = gf * c + gi * gc;
    const float h = go * tanhf(c);
    hb[(size_t)((s & 1) ^ 1) * 256 * 64 + (size_t)u * 64 + lane] = h;
    out[((size_t)t * 512 + (size_t)d * 256 + u) * 64 + lane] = h;
    __syncthreads();  // all WG writes done before signaling
    if (threadIdx.x == 0)
      __hip_atomic_store(&fl[(size_t)s * 64 + g], 1, __ATOMIC_RELEASE,
                         __HIP_MEMORY_SCOPE_AGENT);
  }
  cs[(size_t)u * 64 + lane] = c;
}

// ------------------------------------------------------------ emission proj
// em[t][b][n] = sum_k out1[t][k][b]*w_out[n][k] + b_out[n]
__global__ __launch_bounds__(256)
void emproj(const float* __restrict__ h1, const float* __restrict__ wo,
            const float* __restrict__ bo, float* __restrict__ em) {
  __shared__ float wsm[32 * 512];  // 64 KB
  const int t = blockIdx.x;
  for (int i = threadIdx.x; i < 32 * 512 / 4; i += 256)
    reinterpret_cast<float4*>(wsm)[i] = reinterpret_cast<const float4*>(wo)[i];
  __syncthreads();
  const int b = threadIdx.x & 63, tg = threadIdx.x >> 6;  // tg: 8 tags each
  float acc[8] = {0, 0, 0, 0, 0, 0, 0, 0};
  const float* hbp = h1 + (size_t)t * 512 * 64 + b;
  #pragma unroll 8
  for (int k = 0; k < 512; ++k) {
    float hv = hbp[(size_t)k * 64];
    #pragma unroll
    for (int j = 0; j < 8; ++j) acc[j] += hv * wsm[(tg * 8 + j) * 512 + k];
  }
  #pragma unroll
  for (int j = 0; j < 8; ++j) {
    int n = tg * 8 + j;
    em[((size_t)t * 64 + b) * 32 + n] = acc[j] + bo[n];
  }
}

// ------------------------------------------------------- CRF loss + Viterbi
// grid=128, 64 thr: blocks 0..63 loss(batch b), 64..127 viterbi(batch b).
__global__ __launch_bounds__(64)
void crf_k(const float* __restrict__ em, const int* __restrict__ labels,
           const float* __restrict__ cs, const float* __restrict__ ce,
           const float* __restrict__ ct, float* __restrict__ dout) {
  __shared__ float trs[32 * 32];
  __shared__ float as_[32];
  __shared__ unsigned char bp[511 * 32];
  const int b = blockIdx.x & 63;
  const bool vit = blockIdx.x >= 64;
  const int lane = threadIdx.x;
  for (int i = lane; i < 1024; i += 64) trs[i] = ct[i];
  __syncthreads();
  const int j = lane & 31, half = lane >> 5, i0 = half * 16;

  if (!vit) {
    float part = 0.f;
    for (int tt = lane; tt < TLEN; tt += 64) {
      int lab = labels[b * TLEN + tt];
      part += em[((size_t)tt * 64 + b) * 32 + lab];
      if (tt) part += trs[labels[b * TLEN + tt - 1] * 32 + lab];
    }
    for (int o = 32; o > 0; o >>= 1) part += __shfl_down(part, o);
    float num = part;  // lane 0
    if (lane == 0) num += cs[labels[b * TLEN]] + ce[labels[b * TLEN + TLEN - 1]];
    if (lane < 32) as_[j] = cs[j] + em[(size_t)b * 32 + j];
    __syncthreads();
    for (int t = 1; t < TLEN; ++t) {
      float m = -1e30f;
      #pragma unroll
      for (int ii = 0; ii < 16; ++ii)
        m = fmaxf(m, as_[i0 + ii] + trs[(i0 + ii) * 32 + j]);
      float s = 0.f;
      #pragma unroll
      for (int ii = 0; ii < 16; ++ii)
        s += expf(as_[i0 + ii] + trs[(i0 + ii) * 32 + j] - m);
      float om = __shfl_xor(m, 32), os = __shfl_xor(s, 32);
      float M = fmaxf(m, om);
      s = s * expf(m - M) + os * expf(om - M);
      float na = M + logf(s) + em[((size_t)t * 64 + b) * 32 + j];
      __syncthreads();
      if (half == 0) as_[j] = na;
      __syncthreads();
    }
    float v = (lane < 32) ? as_[j] + ce[j] : -1e30f;
    float m = v;
    for (int o = 32; o > 0; o >>= 1) m = fmaxf(m, __shfl_xor(m, o));
    float s = (lane < 32) ? expf(v - m) : 0.f;
    for (int o = 32; o > 0; o >>= 1) s += __shfl_xor(s, o);
    if (lane == 0) atomicAdd(dout, -(num - (m + logf(s))));
  } else {
    if (lane < 32) as_[j] = cs[j] + em[(size_t)b * 32 + j];
    __syncthreads();
    for (int t = 1; t < TLEN; ++t) {
      float m = -1e30f; int am = 0;
      #pragma unroll
      for (int ii = 0; ii < 16; ++ii) {
        float v = as_[i0 + ii] + trs[(i0 + ii) * 32 + j];
        if (v > m) { m = v; am = i0 + ii; }
      }
      float om = __shfl_xor(m, 32); int oam = __shfl_xor(am, 32);
      float M; int AM;
      if (half == 0) { if (om > m) { M = om; AM = oam; } else { M = m; AM = am; } }
      else           { if (m > om) { M = m; AM = am; } else { M = om; AM = oam; } }
      float na = M + em[((size_t)t * 64 + b) * 32 + j];
      if (half == 0) bp[(t - 1) * 32 + j] = (unsigned char)AM;
      __syncthreads();
      if (half == 0) as_[j] = na;
      __syncthreads();
    }
    float v = (lane < 32) ? as_[j] + ce[j] : -1e30f;
    int aj = (lane < 32) ? j : 0;
    #pragma unroll
    for (int o = 1; o < 64; o <<= 1) {
      float ov = __shfl_xor(v, o); int oa = __shfl_xor(aj, o);
      if (ov > v || (ov == v && oa < aj)) { v = ov; aj = oa; }
    }
    if (lane == 0) {
      int cur = aj;
      dout[1 + b * TLEN + TLEN - 1] = (float)cur;
      for (int t = TLEN - 1; t >= 1; --t) {
        cur = bp[(t - 1) * 32 + cur];
        dout[1 + b * TLEN + t - 1] = (float)cur;
      }
    }
  }
}

// --------------------------------------------------------------------- launch
extern "C" void kernel_launch(void* const* d_in, const int* in_sizes, int n_in,
                              void* d_out, int out_size, void* d_ws, size_t ws_size,
                              hipStream_t stream) {
  (void)in_sizes; (void)n_in;
  float* dout = (float*)d_out;
  if (ws_size < WS_FLOATS * sizeof(float)) {  // diagnostic, not a fault
    ws_too_small_k<<<(out_size + 255) / 256, 256, 0, stream>>>(dout, out_size);
    return;
  }
  const int* ids    = (const int*)d_in[0];
  const int* labels = (const int*)d_in[1];
  const float* emb  = (const float*)d_in[3];
  const float* wih0f = (const float*)d_in[4],  *whh0f = (const float*)d_in[5],  *b0f = (const float*)d_in[6];
  const float* wih0b = (const float*)d_in[7],  *whh0b = (const float*)d_in[8],  *b0b = (const float*)d_in[9];
  const float* wih1f = (const float*)d_in[10], *whh1f = (const float*)d_in[11], *b1f = (const float*)d_in[12];
  const float* wih1b = (const float*)d_in[13], *whh1b = (const float*)d_in[14], *b1b = (const float*)d_in[15];
  const float* w_out = (const float*)d_in[16], *b_out = (const float*)d_in[17];
  const float* c_s = (const float*)d_in[18], *c_e = (const float*)d_in[19], *c_t = (const float*)d_in[20];
  float* ws   = (float*)d_ws;
  float* out0 = ws + O_OUT0;
  float* out1 = ws + O_OUT1;
  float* xg   = ws + O_XG;
  float* em   = ws + O_EM;
  float* hbuf = ws + O_HBUF;
  float* cst  = ws + O_CST;
  int*   flg  = (int*)(ws + O_FLG);

  initz<<<512, 256, 0, stream>>>(hbuf, cst, flg, dout);
  for (int k = 0; k < NCH; ++k) {
    gemm_xg<256, 0><<<dim3(32, 8, 2), 256, 0, stream>>>(emb, ids, wih0f, wih0b, b0f, b0b, xg, k * CS);
    lstm_rec<<<128, 256, 0, stream>>>(xg, whh0f, whh0b, out0, hbuf, cst, flg, k * CS);
  }
  for (int k = 0; k < NCH; ++k) {
    gemm_xg<512, 1><<<dim3(32, 8, 2), 256, 0, stream>>>(out0, nullptr, wih1f, wih1b, b1f, b1b, xg, k * CS);
    lstm_rec<<<128, 256, 0, stream>>>(xg, whh1f, whh1b, out1,
                                      hbuf + (size_t)2 * 2 * 256 * 64,
                                      cst + (size_t)2 * 256 * 64,
                                      flg + (size_t)2 * TLEN * 64, k * CS);
  }
  emproj<<<512, 256, 0, stream>>>(out1, w_out, b_out, em);
  crf_k<<<128, 64, 0, stream>>>(em, labels, c_s, c_e, c_t, dout);
}